// Round 16
// baseline (52.201 us; speedup 1.0000x reference)
//
#include <hip/hip_runtime.h>

// SSIM loss v15: v14 (9-tap, sum/diff channels, DPP halo, 1-wave blocks)
// with TH=8: 5120 waves = exactly 5 waves/SIMD resident (VGPR=60 allows 8),
// +25% TLP for dependency-stall filling at +5% load overhead.

namespace {
constexpr int W = 320, H = 320, B = 128;
constexpr int TH = 8;
constexpr int NSTRIPE = H / TH;     // 40
constexpr int NWAVE = B * NSTRIPE;  // 5120
constexpr int ITERS = TH / 2;       // 4
constexpr float C1 = 1.0e-4f;
constexpr float C2 = 9.0e-4f;
constexpr int NSLOT = 128;
constexpr int SSTR = 16;
}

typedef _Float16 h2 __attribute__((ext_vector_type(2)));

__device__ __forceinline__ float fdot2f(h2 a, h2 b, float c) {
#if __has_builtin(__builtin_amdgcn_fdot2)
  return __builtin_amdgcn_fdot2(a, b, c, false);
#else
  return fmaf((float)a.x, (float)b.x, fmaf((float)a.y, (float)b.y, c));
#endif
}

__device__ __forceinline__ float rcpf(float x) {
  float r;
  asm("v_rcp_f32 %0, %1" : "=v"(r) : "v"(x));
  return r;
}

__device__ __forceinline__ h2 pack2(float a, float b) {
  return h2{(_Float16)a, (_Float16)b};
}

__device__ __forceinline__ h2 pkrtz(float a, float b) {
#if __has_builtin(__builtin_amdgcn_cvt_pkrtz)
  return __builtin_bit_cast(h2, __builtin_amdgcn_cvt_pkrtz(a, b));
#else
  return pack2(a, b);
#endif
}

// lane i <- lane i-1, lane 0 <- 0 (wave_shr:1, bound_ctrl). [HW-verified]
__device__ __forceinline__ h2 dpp_up1(h2 v) {
  int r = __builtin_amdgcn_update_dpp(0, __builtin_bit_cast(int, v),
                                      0x138, 0xF, 0xF, true);
  return __builtin_bit_cast(h2, r);
}
// lane i <- lane i+1, lane 63 <- 0 (wave_shl:1, bound_ctrl). [HW-verified]
__device__ __forceinline__ h2 dpp_dn1(h2 v) {
  int r = __builtin_amdgcn_update_dpp(0, __builtin_bit_cast(int, v),
                                      0x130, 0xF, 0xF, true);
  return __builtin_bit_cast(h2, r);
}

#define LOADP_RAW(ROW, A0, B0, A1, B1)                                        \
  do {                                                                        \
    const int r0_ = (ROW);                                                    \
    if (r0_ >= 0 && r0_ < H) {                                                \
      const float* p_ = P + r0_ * W;                                          \
      const float* t_ = T + r0_ * W;                                          \
      _Pragma("unroll") for (int c_ = 0; c_ < 5; ++c_) {                      \
        A0[c_] = p_[c_]; B0[c_] = t_[c_];                                     \
      }                                                                       \
    } else {                                                                  \
      _Pragma("unroll") for (int c_ = 0; c_ < 5; ++c_) {                      \
        A0[c_] = 0.f; B0[c_] = 0.f;                                           \
      }                                                                       \
    }                                                                         \
    if (r0_ + 1 >= 0 && r0_ + 1 < H) {                                        \
      const float* p_ = P + (r0_ + 1) * W;                                    \
      const float* t_ = T + (r0_ + 1) * W;                                    \
      _Pragma("unroll") for (int c_ = 0; c_ < 5; ++c_) {                      \
        A1[c_] = p_[c_]; B1[c_] = t_[c_];                                     \
      }                                                                       \
    } else {                                                                  \
      _Pragma("unroll") for (int c_ = 0; c_ < 5; ++c_) {                      \
        A1[c_] = 0.f; B1[c_] = 0.f;                                           \
      }                                                                       \
    }                                                                         \
  } while (0)

// Pack (p,t) row-pair -> (s,d) ring slot: s=(p+t)/2, d=(p-t)/2 in packed f16.
#define PACKTO(J, A0, B0, A1, B1)                                             \
  do {                                                                        \
    _Pragma("unroll") for (int c_ = 0; c_ < 5; ++c_) {                        \
      const h2 hp_ = pkrtz(A0[c_], A1[c_]);                                   \
      const h2 ht_ = pkrtz(B0[c_], B1[c_]);                                   \
      rs[J][c_] = (hp_ + ht_) * H05;                                          \
      rd[J][c_] = (hp_ - ht_) * H05;                                          \
    }                                                                         \
  } while (0)

#define HALO(PKc, L, R)                                                       \
  do {                                                                        \
    _Pragma("unroll") for (int c_ = 0; c_ < 5; ++c_) {                        \
      L[c_] = dpp_up1(PKc[c_]);                                               \
      R[c_] = dpp_dn1(PKc[c_]);                                               \
    }                                                                         \
  } while (0)

// 9-tap horizontal blur: output col c reads cols c-4..c+4.
#define XCOL(PKc, L, R, G)                                                    \
  (((G) < 0) ? L[(G) + 5] : (((G) <= 4) ? PKc[(G)] : R[(G) - 5]))

#define HBLUR9(PKc, L, R, O)                                                  \
  do {                                                                        \
    _Pragma("unroll") for (int c_ = 0; c_ < 5; ++c_) {                        \
      h2 s1_ = W9H[0] * XCOL(PKc, L, R, c_ - 4);                              \
      _Pragma("unroll") for (int k_ = 1; k_ <= 4; ++k_)                       \
        s1_ = W9H[k_] * XCOL(PKc, L, R, c_ - 4 + k_) + s1_;                   \
      h2 s2_ = W9H[8] * XCOL(PKc, L, R, c_ + 4);                              \
      _Pragma("unroll") for (int k_ = 7; k_ >= 5; --k_)                       \
        s2_ = W9H[k_] * XCOL(PKc, L, R, c_ - 4 + k_) + s2_;                   \
      O[c_] = s1_ + s2_;                                                      \
    }                                                                         \
  } while (0)

__global__ __launch_bounds__(64) void ssim_main(
    const float* __restrict__ pred, const float* __restrict__ targ,
    float* __restrict__ sink, int slotmask, int sstr) {
  const int lane = threadIdx.x & 63;
  const int stripe = blockIdx.x;
  const int img = stripe / NSTRIPE;
  const int y0  = (stripe % NSTRIPE) * TH;

  const float* __restrict__ P = pred + (size_t)img * (W * H) + 5 * lane;
  const float* __restrict__ T = targ + (size_t)img * (W * H) + 5 * lane;

  // 9-tap truncated + renormalized Gaussian (sigma=1.5).
  constexpr float W9[9] = {0.00761451f, 0.03607501f, 0.10958607f, 0.21344455f,
                           0.26655996f, 0.21344455f, 0.10958607f, 0.03607501f,
                           0.00761451f};
  const h2 wAv[5] = {pack2(W9[0], W9[1]), pack2(W9[2], W9[3]),
                     pack2(W9[4], W9[5]), pack2(W9[6], W9[7]),
                     pack2(W9[8], 0.f)};
  const h2 wBv[5] = {pack2(0.f, W9[0]),   pack2(W9[1], W9[2]),
                     pack2(W9[3], W9[4]), pack2(W9[5], W9[6]),
                     pack2(W9[7], W9[8])};
  h2 W9H[9];
#pragma unroll
  for (int k = 0; k < 9; ++k) W9H[k] = pack2(W9[k], W9[k]);
  const h2 H05 = pack2(0.5f, 0.5f);

  // Ring: 5 row-pairs, (s,d) packed (rowA,rowB) per col.
  h2 rs[5][5], rd[5][5];
  float nfA[5], ntA[5], nfB[5], ntB[5];

  // ---- staggered preamble: slots 1..4 <- pairs (y0-4,y0-2,y0,y0+2);
  //      prefetch regs <- pair (y0+4,y0+5). Slot 0 filled by first slide. ----
  {
    float aA[5], bA[5], cA[5], dA[5];
    float aB[5], bB[5], cB[5], dB[5];
    LOADP_RAW(y0 - 4, aA, bA, cA, dA);
    LOADP_RAW(y0 - 2, aB, bB, cB, dB);
    PACKTO(1, aA, bA, cA, dA);
    LOADP_RAW(y0 + 0, aA, bA, cA, dA);
    PACKTO(2, aB, bB, cB, dB);
    LOADP_RAW(y0 + 2, aB, bB, cB, dB);
    PACKTO(3, aA, bA, cA, dA);
    LOADP_RAW(y0 + 4, nfA, ntA, nfB, ntB);
    PACKTO(4, aB, bB, cB, dB);
  }

  float acc = 0.f;

#pragma unroll 1
  for (int it = 0; it < ITERS; ++it) {
    // slide ring; pack last prefetch; issue next loads.
#pragma unroll
    for (int j = 0; j < 4; ++j)
#pragma unroll
      for (int c = 0; c < 5; ++c) {
        rs[j][c] = rs[j + 1][c];
        rd[j][c] = rd[j + 1][c];
      }
    PACKTO(4, nfA, ntA, nfB, ntB);
    if (it + 1 < ITERS) LOADP_RAW(y0 + 2 * it + 6, nfA, ntA, nfB, ntB);

    // ---- vertical 9-tap blur: 4 channels {s,d,ss,dd}, 5 pair-iters ----
    h2 PK[4][5];  // [ch][col], two output rows packed
#pragma unroll
    for (int c = 0; c < 5; ++c) {
      float sA = 0, dA = 0, ssA = 0, ddA = 0;
      float sB = 0, dB = 0, ssB = 0, ddB = 0;
#pragma unroll
      for (int j = 0; j < 5; ++j) {
        const h2 a = rs[j][c], b = rd[j][c];
        const h2 aa = a * a, bb = b * b;
        const h2 wa = wAv[j], wb = wBv[j];
        sA  = fdot2f(wa, a, sA);
        dA  = fdot2f(wa, b, dA);
        ssA = fdot2f(wa, aa, ssA);
        ddA = fdot2f(wa, bb, ddA);
        sB  = fdot2f(wb, a, sB);
        dB  = fdot2f(wb, b, dB);
        ssB = fdot2f(wb, aa, ssB);
        ddB = fdot2f(wb, bb, ddB);
      }
      PK[0][c] = pkrtz(sA, sB);
      PK[1][c] = pkrtz(dA, dB);
      PK[2][c] = pkrtz(ssA, ssB);
      PK[3][c] = pkrtz(ddA, ddB);
    }

    // ---- horizontal 9-tap blur: DPP halo + pk_fma, 4 channels ----
    h2 OUT[4][5];
#pragma unroll
    for (int ch = 0; ch < 4; ++ch) {
      h2 L[5], R[5];
      HALO(PK[ch], L, R);
      HBLUR9(PK[ch], L, R, OUT[ch]);
    }

    // ---- SSIM from {U,V,w,x}: mx=U+V my=U-V ----
#pragma unroll
    for (int c = 0; c < 5; ++c) {
#pragma unroll
      for (int r = 0; r < 2; ++r) {
        const float u = r ? (float)OUT[0][c].y : (float)OUT[0][c].x;  // U
        const float v = r ? (float)OUT[1][c].y : (float)OUT[1][c].x;  // V
        const float w = r ? (float)OUT[2][c].y : (float)OUT[2][c].x;  // E[ss]
        const float x = r ? (float)OUT[3][c].y : (float)OUT[3][c].x;  // E[dd]
        const float uu = u * u, vv = v * v;
        const float A  = uu + vv;        // (mxx+myy)/2
        const float Bq = uu - vv;        // mxy
        const float num1 = fmaf(2.f, Bq, C1);             // 2mxy+C1
        const float num2 = fmaf(2.f, (w - x) - Bq, C2);   // 2vxy+C2
        const float den1 = fmaf(2.f, A, C1);              // mxx+myy+C1
        const float den2 = fmaf(2.f, (w + x) - A, C2);    // vx+vy+C2
        acc = fmaf(num1 * num2, rcpf(den1 * den2), acc);
      }
    }
  }

  // ---- wave reduce + spread atomics ----
#pragma unroll
  for (int off = 32; off; off >>= 1) acc += __shfl_xor(acc, off, 64);
  if (lane == 0) atomicAdd(sink + (stripe & slotmask) * sstr, acc);
}

__global__ void ssim_final(const float* __restrict__ sink, int nslot, int sstr,
                           float* __restrict__ out) {
  const int tid = threadIdx.x;  // 64 threads
  float v = 0.f;
  for (int s = tid; s < nslot; s += 64) v += sink[s * sstr];
#pragma unroll
  for (int off = 32; off; off >>= 1) v += __shfl_xor(v, off, 64);
  if (tid == 0) out[0] = 1.f - v / 13107200.f;
}

extern "C" void kernel_launch(void* const* d_in, const int* in_sizes, int n_in,
                              void* d_out, int out_size, void* d_ws, size_t ws_size,
                              hipStream_t stream) {
  (void)in_sizes; (void)n_in; (void)out_size;
  const float* pred = (const float*)d_in[0];
  const float* targ = (const float*)d_in[1];
  float* out = (float*)d_out;

  float* sink;
  int nslot, sstr;
  const size_t need = (size_t)NSLOT * SSTR * sizeof(float);
  if (ws_size >= need) {
    sink = (float*)d_ws;
    nslot = NSLOT;
    sstr = SSTR;
  } else {
    sink = out;
    nslot = 1;
    sstr = 0;
  }
  (void)hipMemsetAsync(sink, 0, nslot == 1 ? sizeof(float) : need, stream);
  ssim_main<<<dim3(NWAVE), dim3(64), 0, stream>>>(pred, targ, sink, nslot - 1, sstr);
  ssim_final<<<1, 64, 0, stream>>>(sink, nslot, sstr, out);
}

// Round 17
// 52.170 us; speedup vs baseline: 1.0006x; 1.0006x over previous
//
#include <hip/hip_runtime.h>

// SSIM loss v16: v15 (9-tap, sum/diff, DPP halo, TH=8, 1-wave blocks) with
// vectorized input loads: dwordx4 + dword per row-signal (2 VMEM vs 5) to
// relieve the per-CU vector-memory address pipe (TA), which instruction
// accounting shows ~3x oversubscribed with scalar 20B-stride gathers.

namespace {
constexpr int W = 320, H = 320, B = 128;
constexpr int TH = 8;
constexpr int NSTRIPE = H / TH;     // 40
constexpr int NWAVE = B * NSTRIPE;  // 5120
constexpr int ITERS = TH / 2;       // 4
constexpr float C1 = 1.0e-4f;
constexpr float C2 = 9.0e-4f;
constexpr int NSLOT = 128;
constexpr int SSTR = 16;
}

typedef _Float16 h2 __attribute__((ext_vector_type(2)));
typedef float f4a __attribute__((ext_vector_type(4), aligned(4)));  // 4B-aligned vec load

__device__ __forceinline__ float fdot2f(h2 a, h2 b, float c) {
#if __has_builtin(__builtin_amdgcn_fdot2)
  return __builtin_amdgcn_fdot2(a, b, c, false);
#else
  return fmaf((float)a.x, (float)b.x, fmaf((float)a.y, (float)b.y, c));
#endif
}

__device__ __forceinline__ float rcpf(float x) {
  float r;
  asm("v_rcp_f32 %0, %1" : "=v"(r) : "v"(x));
  return r;
}

__device__ __forceinline__ h2 pack2(float a, float b) {
  return h2{(_Float16)a, (_Float16)b};
}

__device__ __forceinline__ h2 pkrtz(float a, float b) {
#if __has_builtin(__builtin_amdgcn_cvt_pkrtz)
  return __builtin_bit_cast(h2, __builtin_amdgcn_cvt_pkrtz(a, b));
#else
  return pack2(a, b);
#endif
}

// lane i <- lane i-1, lane 0 <- 0 (wave_shr:1, bound_ctrl). [HW-verified]
__device__ __forceinline__ h2 dpp_up1(h2 v) {
  int r = __builtin_amdgcn_update_dpp(0, __builtin_bit_cast(int, v),
                                      0x138, 0xF, 0xF, true);
  return __builtin_bit_cast(h2, r);
}
// lane i <- lane i+1, lane 63 <- 0 (wave_shl:1, bound_ctrl). [HW-verified]
__device__ __forceinline__ h2 dpp_dn1(h2 v) {
  int r = __builtin_amdgcn_update_dpp(0, __builtin_bit_cast(int, v),
                                      0x130, 0xF, 0xF, true);
  return __builtin_bit_cast(h2, r);
}

// Vectorized row-pair load: per row-signal one dwordx4 (cols 0..3) + one
// dword (col 4). 20B/lane base is 4-aligned; gfx9xx multi-dword loads need
// only dword alignment.
#define LOADROW_V(PTR, A)                                                     \
  do {                                                                        \
    const f4a q_ = *(const f4a*)(PTR);                                        \
    A[0] = q_.x; A[1] = q_.y; A[2] = q_.z; A[3] = q_.w;                       \
    A[4] = (PTR)[4];                                                          \
  } while (0)

#define LOADP_RAW(ROW, A0, B0, A1, B1)                                        \
  do {                                                                        \
    const int r0_ = (ROW);                                                    \
    if (r0_ >= 0 && r0_ < H) {                                                \
      LOADROW_V(P + r0_ * W, A0);                                             \
      LOADROW_V(T + r0_ * W, B0);                                             \
    } else {                                                                  \
      _Pragma("unroll") for (int c_ = 0; c_ < 5; ++c_) {                      \
        A0[c_] = 0.f; B0[c_] = 0.f;                                           \
      }                                                                       \
    }                                                                         \
    if (r0_ + 1 >= 0 && r0_ + 1 < H) {                                        \
      LOADROW_V(P + (r0_ + 1) * W, A1);                                       \
      LOADROW_V(T + (r0_ + 1) * W, B1);                                       \
    } else {                                                                  \
      _Pragma("unroll") for (int c_ = 0; c_ < 5; ++c_) {                      \
        A1[c_] = 0.f; B1[c_] = 0.f;                                           \
      }                                                                       \
    }                                                                         \
  } while (0)

// Pack (p,t) row-pair -> (s,d) ring slot: s=(p+t)/2, d=(p-t)/2 in packed f16.
#define PACKTO(J, A0, B0, A1, B1)                                             \
  do {                                                                        \
    _Pragma("unroll") for (int c_ = 0; c_ < 5; ++c_) {                        \
      const h2 hp_ = pkrtz(A0[c_], A1[c_]);                                   \
      const h2 ht_ = pkrtz(B0[c_], B1[c_]);                                   \
      rs[J][c_] = (hp_ + ht_) * H05;                                          \
      rd[J][c_] = (hp_ - ht_) * H05;                                          \
    }                                                                         \
  } while (0)

#define HALO(PKc, L, R)                                                       \
  do {                                                                        \
    _Pragma("unroll") for (int c_ = 0; c_ < 5; ++c_) {                        \
      L[c_] = dpp_up1(PKc[c_]);                                               \
      R[c_] = dpp_dn1(PKc[c_]);                                               \
    }                                                                         \
  } while (0)

// 9-tap horizontal blur: output col c reads cols c-4..c+4.
#define XCOL(PKc, L, R, G)                                                    \
  (((G) < 0) ? L[(G) + 5] : (((G) <= 4) ? PKc[(G)] : R[(G) - 5]))

#define HBLUR9(PKc, L, R, O)                                                  \
  do {                                                                        \
    _Pragma("unroll") for (int c_ = 0; c_ < 5; ++c_) {                        \
      h2 s1_ = W9H[0] * XCOL(PKc, L, R, c_ - 4);                              \
      _Pragma("unroll") for (int k_ = 1; k_ <= 4; ++k_)                       \
        s1_ = W9H[k_] * XCOL(PKc, L, R, c_ - 4 + k_) + s1_;                   \
      h2 s2_ = W9H[8] * XCOL(PKc, L, R, c_ + 4);                              \
      _Pragma("unroll") for (int k_ = 7; k_ >= 5; --k_)                       \
        s2_ = W9H[k_] * XCOL(PKc, L, R, c_ - 4 + k_) + s2_;                   \
      O[c_] = s1_ + s2_;                                                      \
    }                                                                         \
  } while (0)

__global__ __launch_bounds__(64) void ssim_main(
    const float* __restrict__ pred, const float* __restrict__ targ,
    float* __restrict__ sink, int slotmask, int sstr) {
  const int lane = threadIdx.x & 63;
  const int stripe = blockIdx.x;
  const int img = stripe / NSTRIPE;
  const int y0  = (stripe % NSTRIPE) * TH;

  const float* __restrict__ P = pred + (size_t)img * (W * H) + 5 * lane;
  const float* __restrict__ T = targ + (size_t)img * (W * H) + 5 * lane;

  // 9-tap truncated + renormalized Gaussian (sigma=1.5).
  constexpr float W9[9] = {0.00761451f, 0.03607501f, 0.10958607f, 0.21344455f,
                           0.26655996f, 0.21344455f, 0.10958607f, 0.03607501f,
                           0.00761451f};
  const h2 wAv[5] = {pack2(W9[0], W9[1]), pack2(W9[2], W9[3]),
                     pack2(W9[4], W9[5]), pack2(W9[6], W9[7]),
                     pack2(W9[8], 0.f)};
  const h2 wBv[5] = {pack2(0.f, W9[0]),   pack2(W9[1], W9[2]),
                     pack2(W9[3], W9[4]), pack2(W9[5], W9[6]),
                     pack2(W9[7], W9[8])};
  h2 W9H[9];
#pragma unroll
  for (int k = 0; k < 9; ++k) W9H[k] = pack2(W9[k], W9[k]);
  const h2 H05 = pack2(0.5f, 0.5f);

  // Ring: 5 row-pairs, (s,d) packed (rowA,rowB) per col.
  h2 rs[5][5], rd[5][5];
  float nfA[5], ntA[5], nfB[5], ntB[5];

  // ---- staggered preamble: slots 1..4 <- pairs (y0-4,y0-2,y0,y0+2);
  //      prefetch regs <- pair (y0+4,y0+5). Slot 0 filled by first slide. ----
  {
    float aA[5], bA[5], cA[5], dA[5];
    float aB[5], bB[5], cB[5], dB[5];
    LOADP_RAW(y0 - 4, aA, bA, cA, dA);
    LOADP_RAW(y0 - 2, aB, bB, cB, dB);
    PACKTO(1, aA, bA, cA, dA);
    LOADP_RAW(y0 + 0, aA, bA, cA, dA);
    PACKTO(2, aB, bB, cB, dB);
    LOADP_RAW(y0 + 2, aB, bB, cB, dB);
    PACKTO(3, aA, bA, cA, dA);
    LOADP_RAW(y0 + 4, nfA, ntA, nfB, ntB);
    PACKTO(4, aB, bB, cB, dB);
  }

  float acc = 0.f;

#pragma unroll 1
  for (int it = 0; it < ITERS; ++it) {
    // slide ring; pack last prefetch; issue next loads.
#pragma unroll
    for (int j = 0; j < 4; ++j)
#pragma unroll
      for (int c = 0; c < 5; ++c) {
        rs[j][c] = rs[j + 1][c];
        rd[j][c] = rd[j + 1][c];
      }
    PACKTO(4, nfA, ntA, nfB, ntB);
    if (it + 1 < ITERS) LOADP_RAW(y0 + 2 * it + 6, nfA, ntA, nfB, ntB);

    // ---- vertical 9-tap blur: 4 channels {s,d,ss,dd}, 5 pair-iters ----
    h2 PK[4][5];  // [ch][col], two output rows packed
#pragma unroll
    for (int c = 0; c < 5; ++c) {
      float sA = 0, dA = 0, ssA = 0, ddA = 0;
      float sB = 0, dB = 0, ssB = 0, ddB = 0;
#pragma unroll
      for (int j = 0; j < 5; ++j) {
        const h2 a = rs[j][c], b = rd[j][c];
        const h2 aa = a * a, bb = b * b;
        const h2 wa = wAv[j], wb = wBv[j];
        sA  = fdot2f(wa, a, sA);
        dA  = fdot2f(wa, b, dA);
        ssA = fdot2f(wa, aa, ssA);
        ddA = fdot2f(wa, bb, ddA);
        sB  = fdot2f(wb, a, sB);
        dB  = fdot2f(wb, b, dB);
        ssB = fdot2f(wb, aa, ssB);
        ddB = fdot2f(wb, bb, ddB);
      }
      PK[0][c] = pkrtz(sA, sB);
      PK[1][c] = pkrtz(dA, dB);
      PK[2][c] = pkrtz(ssA, ssB);
      PK[3][c] = pkrtz(ddA, ddB);
    }

    // ---- horizontal 9-tap blur: DPP halo + pk_fma, 4 channels ----
    h2 OUT[4][5];
#pragma unroll
    for (int ch = 0; ch < 4; ++ch) {
      h2 L[5], R[5];
      HALO(PK[ch], L, R);
      HBLUR9(PK[ch], L, R, OUT[ch]);
    }

    // ---- SSIM from {U,V,w,x}: mx=U+V my=U-V ----
#pragma unroll
    for (int c = 0; c < 5; ++c) {
#pragma unroll
      for (int r = 0; r < 2; ++r) {
        const float u = r ? (float)OUT[0][c].y : (float)OUT[0][c].x;  // U
        const float v = r ? (float)OUT[1][c].y : (float)OUT[1][c].x;  // V
        const float w = r ? (float)OUT[2][c].y : (float)OUT[2][c].x;  // E[ss]
        const float x = r ? (float)OUT[3][c].y : (float)OUT[3][c].x;  // E[dd]
        const float uu = u * u, vv = v * v;
        const float A  = uu + vv;        // (mxx+myy)/2
        const float Bq = uu - vv;        // mxy
        const float num1 = fmaf(2.f, Bq, C1);             // 2mxy+C1
        const float num2 = fmaf(2.f, (w - x) - Bq, C2);   // 2vxy+C2
        const float den1 = fmaf(2.f, A, C1);              // mxx+myy+C1
        const float den2 = fmaf(2.f, (w + x) - A, C2);    // vx+vy+C2
        acc = fmaf(num1 * num2, rcpf(den1 * den2), acc);
      }
    }
  }

  // ---- wave reduce + spread atomics ----
#pragma unroll
  for (int off = 32; off; off >>= 1) acc += __shfl_xor(acc, off, 64);
  if (lane == 0) atomicAdd(sink + (stripe & slotmask) * sstr, acc);
}

__global__ void ssim_final(const float* __restrict__ sink, int nslot, int sstr,
                           float* __restrict__ out) {
  const int tid = threadIdx.x;  // 64 threads
  float v = 0.f;
  for (int s = tid; s < nslot; s += 64) v += sink[s * sstr];
#pragma unroll
  for (int off = 32; off; off >>= 1) v += __shfl_xor(v, off, 64);
  if (tid == 0) out[0] = 1.f - v / 13107200.f;
}

extern "C" void kernel_launch(void* const* d_in, const int* in_sizes, int n_in,
                              void* d_out, int out_size, void* d_ws, size_t ws_size,
                              hipStream_t stream) {
  (void)in_sizes; (void)n_in; (void)out_size;
  const float* pred = (const float*)d_in[0];
  const float* targ = (const float*)d_in[1];
  float* out = (float*)d_out;

  float* sink;
  int nslot, sstr;
  const size_t need = (size_t)NSLOT * SSTR * sizeof(float);
  if (ws_size >= need) {
    sink = (float*)d_ws;
    nslot = NSLOT;
    sstr = SSTR;
  } else {
    sink = out;
    nslot = 1;
    sstr = 0;
  }
  (void)hipMemsetAsync(sink, 0, nslot == 1 ? sizeof(float) : need, stream);
  ssim_main<<<dim3(NWAVE), dim3(64), 0, stream>>>(pred, targ, sink, nslot - 1, sstr);
  ssim_final<<<1, 64, 0, stream>>>(sink, nslot, sstr, out);
}

// Round 18
// 50.079 us; speedup vs baseline: 1.0424x; 1.0418x over previous
//
#include <hip/hip_runtime.h>

// SSIM loss v17: v15 base (9-tap, sum/diff, DPP halo, TH=8, 1-wave blocks) +
// (1) packed-f16 SSIM epilogue (pk ops on row-pairs, unpack only NUM/DEN),
// (2) unscaled s'=p+t, d'=p-t (the /2 folds into epilogue constants),
// (3) block-of-2 iterations: static windows slots 0-4 / 1-5, single
//     slide-by-2 per kernel, 2 loop trips. ~145 fewer inst/iter.

namespace {
constexpr int W = 320, H = 320, B = 128;
constexpr int TH = 8;
constexpr int NSTRIPE = H / TH;     // 40
constexpr int NWAVE = B * NSTRIPE;  // 5120
constexpr float C1 = 1.0e-4f;
constexpr float C2 = 9.0e-4f;
constexpr int NSLOT = 128;
constexpr int SSTR = 16;
}

typedef _Float16 h2 __attribute__((ext_vector_type(2)));
typedef float f4a __attribute__((ext_vector_type(4), aligned(4)));

__device__ __forceinline__ float fdot2f(h2 a, h2 b, float c) {
#if __has_builtin(__builtin_amdgcn_fdot2)
  return __builtin_amdgcn_fdot2(a, b, c, false);
#else
  return fmaf((float)a.x, (float)b.x, fmaf((float)a.y, (float)b.y, c));
#endif
}

__device__ __forceinline__ float rcpf(float x) {
  float r;
  asm("v_rcp_f32 %0, %1" : "=v"(r) : "v"(x));
  return r;
}

__device__ __forceinline__ h2 pack2(float a, float b) {
  return h2{(_Float16)a, (_Float16)b};
}

__device__ __forceinline__ h2 pkrtz(float a, float b) {
#if __has_builtin(__builtin_amdgcn_cvt_pkrtz)
  return __builtin_bit_cast(h2, __builtin_amdgcn_cvt_pkrtz(a, b));
#else
  return pack2(a, b);
#endif
}

// lane i <- lane i-1, lane 0 <- 0 (wave_shr:1, bound_ctrl). [HW-verified]
__device__ __forceinline__ h2 dpp_up1(h2 v) {
  int r = __builtin_amdgcn_update_dpp(0, __builtin_bit_cast(int, v),
                                      0x138, 0xF, 0xF, true);
  return __builtin_bit_cast(h2, r);
}
// lane i <- lane i+1, lane 63 <- 0 (wave_shl:1, bound_ctrl). [HW-verified]
__device__ __forceinline__ h2 dpp_dn1(h2 v) {
  int r = __builtin_amdgcn_update_dpp(0, __builtin_bit_cast(int, v),
                                      0x130, 0xF, 0xF, true);
  return __builtin_bit_cast(h2, r);
}

#define LOADROW_V(PTR, A)                                                     \
  do {                                                                        \
    const f4a q_ = *(const f4a*)(PTR);                                        \
    A[0] = q_.x; A[1] = q_.y; A[2] = q_.z; A[3] = q_.w;                       \
    A[4] = (PTR)[4];                                                          \
  } while (0)

#define LOADP_RAW(ROW, A0, B0, A1, B1)                                        \
  do {                                                                        \
    const int r0_ = (ROW);                                                    \
    if (r0_ >= 0 && r0_ < H) {                                                \
      LOADROW_V(P + r0_ * W, A0);                                             \
      LOADROW_V(T + r0_ * W, B0);                                             \
    } else {                                                                  \
      _Pragma("unroll") for (int c_ = 0; c_ < 5; ++c_) {                      \
        A0[c_] = 0.f; B0[c_] = 0.f;                                           \
      }                                                                       \
    }                                                                         \
    if (r0_ + 1 >= 0 && r0_ + 1 < H) {                                        \
      LOADROW_V(P + (r0_ + 1) * W, A1);                                       \
      LOADROW_V(T + (r0_ + 1) * W, B1);                                       \
    } else {                                                                  \
      _Pragma("unroll") for (int c_ = 0; c_ < 5; ++c_) {                      \
        A1[c_] = 0.f; B1[c_] = 0.f;                                           \
      }                                                                       \
    }                                                                         \
  } while (0)

// Pack (p,t) row-pair -> (s',d') ring slot: s'=p+t, d'=p-t (no /2; it folds
// into the epilogue constants).
#define PACKTO(J, A0, B0, A1, B1)                                             \
  do {                                                                        \
    _Pragma("unroll") for (int c_ = 0; c_ < 5; ++c_) {                        \
      const h2 hp_ = pkrtz(A0[c_], A1[c_]);                                   \
      const h2 ht_ = pkrtz(B0[c_], B1[c_]);                                   \
      rs[J][c_] = hp_ + ht_;                                                  \
      rd[J][c_] = hp_ - ht_;                                                  \
    }                                                                         \
  } while (0)

#define HALO(PKc, L, R)                                                       \
  do {                                                                        \
    _Pragma("unroll") for (int c_ = 0; c_ < 5; ++c_) {                        \
      L[c_] = dpp_up1(PKc[c_]);                                               \
      R[c_] = dpp_dn1(PKc[c_]);                                               \
    }                                                                         \
  } while (0)

// 9-tap horizontal blur: output col c reads cols c-4..c+4.
#define XCOL(PKc, L, R, G)                                                    \
  (((G) < 0) ? L[(G) + 5] : (((G) <= 4) ? PKc[(G)] : R[(G) - 5]))

#define HBLUR9(PKc, L, R, O)                                                  \
  do {                                                                        \
    _Pragma("unroll") for (int c_ = 0; c_ < 5; ++c_) {                        \
      h2 s1_ = W9H[0] * XCOL(PKc, L, R, c_ - 4);                              \
      _Pragma("unroll") for (int k_ = 1; k_ <= 4; ++k_)                       \
        s1_ = W9H[k_] * XCOL(PKc, L, R, c_ - 4 + k_) + s1_;                   \
      h2 s2_ = W9H[8] * XCOL(PKc, L, R, c_ + 4);                              \
      _Pragma("unroll") for (int k_ = 7; k_ >= 5; --k_)                       \
        s2_ = W9H[k_] * XCOL(PKc, L, R, c_ - 4 + k_) + s2_;                   \
      O[c_] = s1_ + s2_;                                                      \
    }                                                                         \
  } while (0)

// One output-row-pair at static window slots I..I+4, packed-f16 epilogue.
// With s'=p+t, d'=p-t: Bq'=4*mxy, A'=2*(mxx+myy), w'-x'=4*E[pt],
// (w'+x'-A')/2 = vx+vy -> num/den in original scale via *0.5 folds.
#define COMPUTE(I)                                                            \
  do {                                                                        \
    h2 PK[4][5];                                                              \
    _Pragma("unroll") for (int c = 0; c < 5; ++c) {                           \
      float sA = 0, dA = 0, ssA = 0, ddA = 0;                                 \
      float sB = 0, dB = 0, ssB = 0, ddB = 0;                                 \
      _Pragma("unroll") for (int j = 0; j < 5; ++j) {                         \
        const h2 a = rs[(I) + j][c], b = rd[(I) + j][c];                      \
        const h2 aa = a * a, bb = b * b;                                      \
        const h2 wa = wAv[j], wb = wBv[j];                                    \
        sA  = fdot2f(wa, a, sA);                                              \
        dA  = fdot2f(wa, b, dA);                                              \
        ssA = fdot2f(wa, aa, ssA);                                            \
        ddA = fdot2f(wa, bb, ddA);                                            \
        sB  = fdot2f(wb, a, sB);                                              \
        dB  = fdot2f(wb, b, dB);                                              \
        ssB = fdot2f(wb, aa, ssB);                                            \
        ddB = fdot2f(wb, bb, ddB);                                            \
      }                                                                       \
      PK[0][c] = pkrtz(sA, sB);                                               \
      PK[1][c] = pkrtz(dA, dB);                                               \
      PK[2][c] = pkrtz(ssA, ssB);                                             \
      PK[3][c] = pkrtz(ddA, ddB);                                             \
    }                                                                         \
    h2 OUT[4][5];                                                             \
    _Pragma("unroll") for (int ch = 0; ch < 4; ++ch) {                        \
      h2 L[5], R[5];                                                          \
      HALO(PK[ch], L, R);                                                     \
      HBLUR9(PK[ch], L, R, OUT[ch]);                                          \
    }                                                                         \
    _Pragma("unroll") for (int c = 0; c < 5; ++c) {                           \
      const h2 U = OUT[0][c], V = OUT[1][c];                                  \
      const h2 w_ = OUT[2][c], x_ = OUT[3][c];                                \
      const h2 uu = U * U, vv = V * V;                                        \
      const h2 Ap = uu + vv, Bq = uu - vv;                                    \
      const h2 n1 = Bq * HALFp + C1p;                 /* 2mxy+C1   */         \
      const h2 n2 = ((w_ - x_) - Bq) * HALFp + C2p;   /* 2vxy+C2   */         \
      const h2 d1 = Ap * HALFp + C1p;                 /* mxx+myy+C1*/         \
      const h2 d2 = ((w_ + x_) - Ap) * HALFp + C2p;   /* vx+vy+C2  */         \
      const h2 NU = n1 * n2, DE = d1 * d2;                                    \
      acc = fmaf((float)NU.x, rcpf((float)DE.x), acc);                        \
      acc = fmaf((float)NU.y, rcpf((float)DE.y), acc);                        \
    }                                                                         \
  } while (0)

__global__ __launch_bounds__(64) void ssim_main(
    const float* __restrict__ pred, const float* __restrict__ targ,
    float* __restrict__ sink, int slotmask, int sstr) {
  const int lane = threadIdx.x & 63;
  const int stripe = blockIdx.x;
  const int img = stripe / NSTRIPE;
  const int y0  = (stripe % NSTRIPE) * TH;

  const float* __restrict__ P = pred + (size_t)img * (W * H) + 5 * lane;
  const float* __restrict__ T = targ + (size_t)img * (W * H) + 5 * lane;

  // 9-tap truncated + renormalized Gaussian (sigma=1.5).
  constexpr float W9[9] = {0.00761451f, 0.03607501f, 0.10958607f, 0.21344455f,
                           0.26655996f, 0.21344455f, 0.10958607f, 0.03607501f,
                           0.00761451f};
  const h2 wAv[5] = {pack2(W9[0], W9[1]), pack2(W9[2], W9[3]),
                     pack2(W9[4], W9[5]), pack2(W9[6], W9[7]),
                     pack2(W9[8], 0.f)};
  const h2 wBv[5] = {pack2(0.f, W9[0]),   pack2(W9[1], W9[2]),
                     pack2(W9[3], W9[4]), pack2(W9[5], W9[6]),
                     pack2(W9[7], W9[8])};
  h2 W9H[9];
#pragma unroll
  for (int k = 0; k < 9; ++k) W9H[k] = pack2(W9[k], W9[k]);
  const h2 HALFp = pack2(0.5f, 0.5f);
  const h2 C1p = pack2(C1, C1);
  const h2 C2p = pack2(C2, C2);

  // Ring: 6 row-pairs, (s',d') packed (rowA,rowB) per col.
  h2 rs[6][5], rd[6][5];

  // ---- staggered preamble: pairs 0..5 -> slots 0..5 ----
  {
    float aA[5], bA[5], cA[5], dA[5];
    float aB[5], bB[5], cB[5], dB[5];
    LOADP_RAW(y0 - 4, aA, bA, cA, dA);
    LOADP_RAW(y0 - 2, aB, bB, cB, dB);
    PACKTO(0, aA, bA, cA, dA);
    LOADP_RAW(y0 + 0, aA, bA, cA, dA);
    PACKTO(1, aB, bB, cB, dB);
    LOADP_RAW(y0 + 2, aB, bB, cB, dB);
    PACKTO(2, aA, bA, cA, dA);
    LOADP_RAW(y0 + 4, aA, bA, cA, dA);
    PACKTO(3, aB, bB, cB, dB);
    LOADP_RAW(y0 + 6, aB, bB, cB, dB);
    PACKTO(4, aA, bA, cA, dA);
    PACKTO(5, aB, bB, cB, dB);
  }

  float acc = 0.f;
  float nfA[5], ntA[5], nfB[5], ntB[5];   // pair 6 prefetch
  float mfA[5], mtA[5], mfB[5], mtB[5];   // pair 7 prefetch

  // Block b=0: outputs (y0..y0+3) from pairs 0-5; prefetch pairs 6,7; slide.
  // Block b=1: outputs (y0+4..y0+7) from pairs 2-7 (now in slots 0-5).
#pragma unroll 1
  for (int b = 0; b < 2; ++b) {
    if (b == 0) LOADP_RAW(y0 + 8, nfA, ntA, nfB, ntB);    // pair 6
    COMPUTE(0);                                           // window slots 0..4
    if (b == 0) LOADP_RAW(y0 + 10, mfA, mtA, mfB, mtB);   // pair 7
    COMPUTE(1);                                           // window slots 1..5
    if (b == 0) {
#pragma unroll
      for (int j = 0; j < 4; ++j)
#pragma unroll
        for (int c = 0; c < 5; ++c) {
          rs[j][c] = rs[j + 2][c];
          rd[j][c] = rd[j + 2][c];
        }
      PACKTO(4, nfA, ntA, nfB, ntB);
      PACKTO(5, mfA, mtA, mfB, mtB);
    }
  }

  // ---- wave reduce + spread atomics ----
#pragma unroll
  for (int off = 32; off; off >>= 1) acc += __shfl_xor(acc, off, 64);
  if (lane == 0) atomicAdd(sink + (stripe & slotmask) * sstr, acc);
}

__global__ void ssim_final(const float* __restrict__ sink, int nslot, int sstr,
                           float* __restrict__ out) {
  const int tid = threadIdx.x;  // 64 threads
  float v = 0.f;
  for (int s = tid; s < nslot; s += 64) v += sink[s * sstr];
#pragma unroll
  for (int off = 32; off; off >>= 1) v += __shfl_xor(v, off, 64);
  if (tid == 0) out[0] = 1.f - v / 13107200.f;
}

extern "C" void kernel_launch(void* const* d_in, const int* in_sizes, int n_in,
                              void* d_out, int out_size, void* d_ws, size_t ws_size,
                              hipStream_t stream) {
  (void)in_sizes; (void)n_in; (void)out_size;
  const float* pred = (const float*)d_in[0];
  const float* targ = (const float*)d_in[1];
  float* out = (float*)d_out;

  float* sink;
  int nslot, sstr;
  const size_t need = (size_t)NSLOT * SSTR * sizeof(float);
  if (ws_size >= need) {
    sink = (float*)d_ws;
    nslot = NSLOT;
    sstr = SSTR;
  } else {
    sink = out;
    nslot = 1;
    sstr = 0;
  }
  (void)hipMemsetAsync(sink, 0, nslot == 1 ? sizeof(float) : need, stream);
  ssim_main<<<dim3(NWAVE), dim3(64), 0, stream>>>(pred, targ, sink, nslot - 1, sstr);
  ssim_final<<<1, 64, 0, stream>>>(sink, nslot, sstr, out);
}